// Round 8
// baseline (169.057 us; speedup 1.0000x reference)
//
#include <hip/hip_runtime.h>

#define DZ 512
#define DT 66048
#define SV_JITTER 1e-4f

typedef __attribute__((ext_vector_type(8))) short bf8;
typedef __attribute__((ext_vector_type(4))) short bf4;
typedef __attribute__((ext_vector_type(4))) float f4;

__device__ __forceinline__ short f2bf(float f) {
  unsigned u = __builtin_bit_cast(unsigned, f);
  return (short)((u + 0x7FFFu + ((u >> 16) & 1u)) >> 16);
}

__device__ __forceinline__ bf8 cvt8(float4 a, float4 b) {
  bf8 r = { f2bf(a.x), f2bf(a.y), f2bf(a.z), f2bf(a.w),
            f2bf(b.x), f2bf(b.y), f2bf(b.z), f2bf(b.w) };
  return r;
}

// tril/jitter cvt: element t has k-index kbase+t
__device__ __forceinline__ bf8 cvt8_tril(float4 x, float4 y, int kbase, int diag) {
  float v[8] = {x.x, x.y, x.z, x.w, y.x, y.y, y.z, y.w};
  bf8 r;
  #pragma unroll
  for (int t = 0; t < 8; ++t) {
    int k = kbase + t;
    float val = (k < diag) ? v[t] : ((k == diag) ? v[t] + SV_JITTER : 0.f);
    r[t] = f2bf(val);
  }
  return r;
}

// 258 blocks x 1024 threads (16 waves, 1 block/CU). Block owns 256 contiguous
// output cols, 4 rounds x 64 cols. Per round: ALL threads stream the round's
// B panel (64 rows x 2KB fp32, fully contiguous) -> bf16 XOR-swizzled LDS
// (double-buffered), tril/jitter applied at stage time. Wave (ws=sample
// group, wc=32-col half): per K-step 1 A-frag (global, L2-hot) + 2 swizzled
// ds_read_b128 + 2 MFMA. acc layout: col=lane&15, row=4*(lane>>4)+reg.
__global__ __launch_bounds__(1024, 4)
void sv_kernel(const float* __restrict__ mv, const float* __restrict__ Lz,
               const float* __restrict__ Ly, const float* __restrict__ Lyz,
               const float* __restrict__ eps, float* __restrict__ out) {
  // panel buffer: row-major [64 rows][512 k] bf16, 1KB/row, 16B slots
  // XOR-swizzled: byte = row*1024 + ((slot ^ (row&7))<<4) + within
  __shared__ short Bp[2][64 * 512];  // 2 x 64 KB

  const int tid = threadIdx.x;
  const int lane = tid & 63;
  const int wv = tid >> 6;   // 0..15
  const int lcol = lane & 15;
  const int q = lane >> 4;
  const int ws = wv >> 1;    // sample group 0..7 (rows 16*ws..+15)
  const int wc = wv & 1;     // 32-col half within the round's 64 cols
  const int B0 = blockIdx.x * 256;
  const bool is_y = (B0 >= DZ);  // blocks 0,1 are pure-z, rest pure-y

  // ---- staging: thread t, slot j covers float4 #f = j*1024+t of the panel
  // (row = f>>7, k0 = (f&127)*4). Global reads: 64 lanes x 16B contiguous.
  float4 sv[8];
  auto stage_issue = [&](int r) {
    const int cbase = B0 + r * 64;
    #pragma unroll
    for (int j = 0; j < 8; ++j) {
      const int f = j * 1024 + tid;
      const int row = f >> 7;
      const int k0 = (f & 127) << 2;
      const int gc = cbase + row;
      const float* src = (gc < DZ) ? (Lz + (size_t)gc * DZ + k0)
                                   : (Lyz + (size_t)(gc - DZ) * DZ + k0);
      sv[j] = *(const float4*)src;
    }
  };
  auto stage_write = [&](int r, short* buf) {
    const int cbase = B0 + r * 64;
    #pragma unroll
    for (int j = 0; j < 8; ++j) {
      const int f = j * 1024 + tid;
      const int row = f >> 7;
      const int k0 = (f & 127) << 2;
      const int gc = cbase + row;
      const float v[4] = {sv[j].x, sv[j].y, sv[j].z, sv[j].w};
      bf4 w;
      if (gc < DZ) {  // z panel: tril + jitter applied at stage time
        #pragma unroll
        for (int t = 0; t < 4; ++t) {
          const int k = k0 + t;
          const float val = (k < gc) ? v[t] : ((k == gc) ? v[t] + SV_JITTER : 0.f);
          w[t] = f2bf(val);
        }
      } else {
        #pragma unroll
        for (int t = 0; t < 4; ++t) w[t] = f2bf(v[t]);
      }
      const int slot = k0 >> 3;  // 16B slot 0..63
      const int off = (row << 10) + ((slot ^ (row & 7)) << 4) + ((k0 & 4) << 1);
      *(bf4*)((char*)buf + off) = w;
    }
  };
  // swizzled B-frag read: frag g of this wave's 32-col half, K-step kk
  auto readB = [&](const short* buf, int g, int kk) -> bf8 {
    const int rowIdx = wc * 32 + 16 * g + lcol;
    const int slot = kk * 4 + q;
    const int off = (rowIdx << 10) + ((slot ^ (rowIdx & 7)) << 4);
    return *(const bf8*)((const char*)buf + off);
  };

  stage_issue(0);
  stage_write(0, Bp[0]);
  __syncthreads();

  const float* arow = eps + (size_t)(16 * ws + lcol) * DT + 8 * q;

  #pragma unroll 1
  for (int r = 0; r < 4; ++r) {
    if (r + 1 < 4) stage_issue(r + 1);
    __builtin_amdgcn_sched_barrier(0);  // pin stage loads ahead of compute

    const short* buf = Bp[r & 1];
    f4 acc[2];
    acc[0] = f4{0.f, 0.f, 0.f, 0.f};
    acc[1] = f4{0.f, 0.f, 0.f, 0.f};

    float4 a0 = *(const float4*)(arow);
    float4 a1 = *(const float4*)(arow + 4);
    #pragma unroll
    for (int kk = 0; kk < 16; ++kk) {
      float4 n0, n1;
      if (kk < 15) {  // A 2-deep prefetch (L2-hot eps_z)
        n0 = *(const float4*)(arow + (kk + 1) * 32);
        n1 = *(const float4*)(arow + (kk + 1) * 32 + 4);
      }
      const bf8 af = cvt8(a0, a1);
      const bf8 b0 = readB(buf, 0, kk);
      const bf8 b1 = readB(buf, 1, kk);
      acc[0] = __builtin_amdgcn_mfma_f32_16x16x32_bf16(af, b0, acc[0], 0, 0, 0);
      acc[1] = __builtin_amdgcn_mfma_f32_16x16x32_bf16(af, b1, acc[1], 0, 0, 0);
      a0 = n0; a1 = n1;
    }

    // block-diag einsum step (y blocks): B from Ly (tril+jitter), A = eps_y
    if (is_y) {
      const int cy = B0 - DZ + r * 64 + wc * 32;  // wave's y-rel col base
      const int n = cy >> 5;                      // 32x32 Ly block (aligned)
      const float* pa = arow + DZ + (size_t)n * 32;
      const float4 da0 = *(const float4*)pa;
      const float4 da1 = *(const float4*)(pa + 4);
      const bf8 af = cvt8(da0, da1);
      #pragma unroll
      for (int g = 0; g < 2; ++g) {
        const int i = 16 * g + lcol;  // row of Ly block = out col within 32
        const float* pb = Ly + ((size_t)n * 32 + i) * 32 + 8 * q;
        const float4 bx = *(const float4*)pb;
        const float4 by = *(const float4*)(pb + 4);
        const bf8 bf = cvt8_tril(bx, by, 8 * q, i);
        acc[g] = __builtin_amdgcn_mfma_f32_16x16x32_bf16(af, bf, acc[g], 0, 0, 0);
      }
    }

    // epilogue for this round's 32 cols
    const int colbase = B0 + r * 64 + wc * 32;
    #pragma unroll
    for (int g = 0; g < 2; ++g) {
      const int col = colbase + 16 * g + lcol;
      const float mval = mv[col];
      #pragma unroll
      for (int rr = 0; rr < 4; ++rr) {
        out[(size_t)(16 * ws + 4 * q + rr) * DT + col] = acc[g][rr] + mval;
      }
    }

    if (r + 1 < 4) stage_write(r + 1, Bp[(r + 1) & 1]);
    __syncthreads();
  }
}

extern "C" void kernel_launch(void* const* d_in, const int* in_sizes, int n_in,
                              void* d_out, int out_size, void* d_ws, size_t ws_size,
                              hipStream_t stream) {
  const float* m   = (const float*)d_in[0];
  const float* Lz  = (const float*)d_in[1];
  const float* Ly  = (const float*)d_in[2];
  const float* Lyz = (const float*)d_in[3];
  const float* eps = (const float*)d_in[4];
  float* out = (float*)d_out;
  sv_kernel<<<dim3(DT / 256), dim3(1024), 0, stream>>>(m, Lz, Ly, Lyz, eps, out);
}